// Round 5
// baseline (550.651 us; speedup 1.0000x reference)
//
#include <hip/hip_runtime.h>

#define IN_DIM 18
#define HID 64
#define EMB 32
#define NGROUP 8   // XCD count; blockIdx.x & 7 ~ XCD id (heuristic, speed-only)
#define PCAP 336   // LDS bin capacity per partition per 1024-edge tile (mean 128)

typedef int vint4 __attribute__((ext_vector_type(4)));
typedef unsigned long long u64;

__device__ inline float4 shfl_xor_f4(float4 v, int m) {
    v.x = __shfl_xor(v.x, m);
    v.y = __shfl_xor(v.y, m);
    v.z = __shfl_xor(v.z, m);
    v.w = __shfl_xor(v.w, m);
    return v;
}

// ---------------- init ----------------

__global__ void k_init(int* __restrict__ deg, int* __restrict__ gcnt, int n) {
    int i = blockIdx.x * 256 + threadIdx.x;
    if (i < n) deg[i] = 1;          // self-loop
    if (i < NGROUP) gcnt[i] = 0;
}

// ---------------- bucketing pass: (dst,src) pairs -> 8 dst-partition buckets --
// pair packed as u64: (src<<32) | dst

__global__ void k_part(const int* __restrict__ src, const int* __restrict__ dst,
                       int* __restrict__ gcnt, u64* __restrict__ gbuf,
                       int e, int nrange, int cap) {
    __shared__ u64 sbuf[NGROUP][PCAP];
    __shared__ int scnt[NGROUP];
    __shared__ int sbase[NGROUP];
    int tid = threadIdx.x;
    int ntile = (e + 1023) >> 10;
    for (int tile = blockIdx.x; tile < ntile; tile += gridDim.x) {
        if (tid < NGROUP) scnt[tid] = 0;
        __syncthreads();
        int i = (tile << 10) + tid * 4;
        if (i + 4 <= e) {
            vint4 s4 = __builtin_nontemporal_load((const vint4*)(src + i));
            vint4 d4 = __builtin_nontemporal_load((const vint4*)(dst + i));
#pragma unroll
            for (int k = 0; k < 4; ++k) {
                int d = d4[k];
                int p = d / nrange;
                u64 pr = ((u64)(unsigned)s4[k] << 32) | (unsigned)d;
                int pos = atomicAdd(&scnt[p], 1);
                if (pos < PCAP) sbuf[p][pos] = pr;
                else {
                    int gpos = atomicAdd(&gcnt[p], 1);
                    __builtin_nontemporal_store(pr, &gbuf[(size_t)p * cap + gpos]);
                }
            }
        } else {
            for (int k = i; k < e; ++k) {
                int d = dst[k];
                int p = d / nrange;
                u64 pr = ((u64)(unsigned)src[k] << 32) | (unsigned)d;
                int pos = atomicAdd(&scnt[p], 1);
                if (pos < PCAP) sbuf[p][pos] = pr;
                else {
                    int gpos = atomicAdd(&gcnt[p], 1);
                    __builtin_nontemporal_store(pr, &gbuf[(size_t)p * cap + gpos]);
                }
            }
        }
        __syncthreads();
        if (tid < NGROUP) sbase[tid] = atomicAdd(&gcnt[tid], min(scnt[tid], PCAP));
        __syncthreads();
#pragma unroll
        for (int p = 0; p < NGROUP; ++p) {
            int c = min(scnt[p], PCAP);
            int b = sbase[p];
            for (int k = tid; k < c; k += 256)
                __builtin_nontemporal_store(sbuf[p][k], &gbuf[(size_t)p * cap + b + k]);
        }
        __syncthreads();
    }
}

// ---------------- partition-local degree count ----------------

__global__ void k_count_b(const u64* __restrict__ gbuf, const int* __restrict__ gcnt,
                          int* __restrict__ deg, int cap) {
    int g = blockIdx.x & (NGROUP - 1);
    int cnt = gcnt[g];
    const u64* buf = gbuf + (size_t)g * cap;
    int i = (blockIdx.x >> 3) * 256 + threadIdx.x;
    int step = (gridDim.x >> 3) * 256;
    for (; i < cnt; i += step) {
        u64 pr = __builtin_nontemporal_load(&buf[i]);
        atomicAdd(&deg[(int)(pr & 0xffffffffu)], 1);
    }
}

__global__ void k_dis(const int* __restrict__ deg, float* __restrict__ dis, int n) {
    int i = blockIdx.x * 256 + threadIdx.x;
    if (i < n) dis[i] = rsqrtf((float)deg[i]);
}

// ---------------- exclusive scan of counts (deg-1) -> row_ptr ----------------

__global__ void k_scanA(const int* __restrict__ deg, int* __restrict__ row_ptr,
                        int* __restrict__ blksums, int n) {
    __shared__ int s[1024];
    int tid = threadIdx.x;
    int i = blockIdx.x * 1024 + tid;
    int v = (i < n) ? (deg[i] - 1) : 0;
    s[tid] = v;
    __syncthreads();
    for (int off = 1; off < 1024; off <<= 1) {
        int t = (tid >= off) ? s[tid - off] : 0;
        __syncthreads();
        s[tid] += t;
        __syncthreads();
    }
    if (i < n) row_ptr[i] = s[tid] - v;       // exclusive within block
    if (tid == 1023) blksums[blockIdx.x] = s[1023];
}

__global__ void k_scanB(const int* __restrict__ blksums, int* __restrict__ blkoffs, int nb) {
    __shared__ int s[1024];
    int tid = threadIdx.x;
    int v = (tid < nb) ? blksums[tid] : 0;
    s[tid] = v;
    __syncthreads();
    for (int off = 1; off < 1024; off <<= 1) {
        int t = (tid >= off) ? s[tid - off] : 0;
        __syncthreads();
        s[tid] += t;
        __syncthreads();
    }
    if (tid < nb) blkoffs[tid] = s[tid] - v;  // exclusive
}

__global__ void k_scanC(int* __restrict__ row_ptr, const int* __restrict__ blkoffs,
                        int* __restrict__ write_ptr, int n) {
    int i = blockIdx.x * 1024 + threadIdx.x;
    if (i < n) {
        int r = row_ptr[i] + blkoffs[blockIdx.x];
        row_ptr[i] = r;
        write_ptr[i] = r;
    }
}

// ---------------- partition-local CSR fill ----------------

__global__ void k_fill_b(const u64* __restrict__ gbuf, const int* __restrict__ gcnt,
                         int* __restrict__ write_ptr, int* __restrict__ adj, int cap) {
    int g = blockIdx.x & (NGROUP - 1);
    int cnt = gcnt[g];
    const u64* buf = gbuf + (size_t)g * cap;
    int i = (blockIdx.x >> 3) * 256 + threadIdx.x;
    int step = (gridDim.x >> 3) * 256;
    for (; i < cnt; i += step) {
        u64 pr = __builtin_nontemporal_load(&buf[i]);
        int d = (int)(pr & 0xffffffffu);
        int slot = atomicAdd(&write_ptr[d], 1);
        adj[slot] = (int)(pr >> 32);
    }
}

// ---------------- legacy fallback (if ws too small for buckets) ----------------

__global__ void k_count_part(const int* __restrict__ dst, int* __restrict__ deg,
                             int e, int nrange, int n) {
    int g  = blockIdx.x & (NGROUP - 1);
    int lo = g * nrange;
    int hi = min(n, lo + nrange);
    int bid  = blockIdx.x >> 3;
    int nblk = gridDim.x >> 3;
    int i0   = (bid * 256 + threadIdx.x) * 4;
    int step = nblk * 256 * 4;
    for (int i = i0; i < e; i += step) {
        if (i + 4 <= e) {
            int4 d4 = *(const int4*)(dst + i);
            if (d4.x >= lo && d4.x < hi) atomicAdd(&deg[d4.x], 1);
            if (d4.y >= lo && d4.y < hi) atomicAdd(&deg[d4.y], 1);
            if (d4.z >= lo && d4.z < hi) atomicAdd(&deg[d4.z], 1);
            if (d4.w >= lo && d4.w < hi) atomicAdd(&deg[d4.w], 1);
        } else {
            for (int k = i; k < e; ++k) {
                int d = dst[k];
                if (d >= lo && d < hi) atomicAdd(&deg[d], 1);
            }
        }
    }
}

__global__ void k_fill_part(const int* __restrict__ src, const int* __restrict__ dst,
                            int* __restrict__ write_ptr, int* __restrict__ adj,
                            int e, int nrange, int n) {
    int g  = blockIdx.x & (NGROUP - 1);
    int lo = g * nrange;
    int hi = min(n, lo + nrange);
    int bid  = blockIdx.x >> 3;
    int nblk = gridDim.x >> 3;
    int i0   = (bid * 256 + threadIdx.x) * 4;
    int step = nblk * 256 * 4;
    for (int i = i0; i < e; i += step) {
        if (i + 4 <= e) {
            int4 d4 = *(const int4*)(dst + i);
            if (d4.x >= lo && d4.x < hi) { int slot = atomicAdd(&write_ptr[d4.x], 1); adj[slot] = src[i];     }
            if (d4.y >= lo && d4.y < hi) { int slot = atomicAdd(&write_ptr[d4.y], 1); adj[slot] = src[i + 1]; }
            if (d4.z >= lo && d4.z < hi) { int slot = atomicAdd(&write_ptr[d4.z], 1); adj[slot] = src[i + 2]; }
            if (d4.w >= lo && d4.w < hi) { int slot = atomicAdd(&write_ptr[d4.w], 1); adj[slot] = src[i + 3]; }
        } else {
            for (int k = i; k < e; ++k) {
                int d = dst[k];
                if (d >= lo && d < hi) { int slot = atomicAdd(&write_ptr[d], 1); adj[slot] = src[k]; }
            }
        }
    }
}

// ---------------- layer GEMMs (dense, tiny K) ----------------

__global__ void k_gemm1(const float* __restrict__ x, const float* __restrict__ W1,
                        const float* __restrict__ dis, float* __restrict__ hn, int n) {
    __shared__ float w[IN_DIM * HID];
    for (int t = threadIdx.x; t < IN_DIM * HID; t += 256) w[t] = W1[t];
    __syncthreads();
    int gid = blockIdx.x * 256 + threadIdx.x;
    int i = gid >> 6, f = gid & 63;
    if (i >= n) return;
    const float* xr = x + (size_t)i * IN_DIM;
    float acc = 0.f;
#pragma unroll
    for (int k = 0; k < IN_DIM; ++k) acc += xr[k] * w[k * HID + f];
    hn[(size_t)i * HID + f] = acc * dis[i];
}

__global__ void k_gemm2(const float* __restrict__ h, const float* __restrict__ W2,
                        const float* __restrict__ dis, float* __restrict__ hn2, int n) {
    __shared__ float w[HID * EMB];
    for (int t = threadIdx.x; t < HID * EMB; t += 256) w[t] = W2[t];
    __syncthreads();
    int gid = blockIdx.x * 256 + threadIdx.x;
    int i = gid >> 5, g = gid & 31;
    if (i >= n) return;
    const float* hr = h + (size_t)i * HID;
    float acc = 0.f;
#pragma unroll
    for (int k = 0; k < HID; ++k) acc += hr[k] * w[k * EMB + g];
    hn2[(size_t)i * EMB + g] = acc * dis[i];
}

// ---------------- aggregation (gather over CSR, float4 per lane) ----------------

__global__ void k_agg1(const float* __restrict__ hn, const int* __restrict__ row_ptr,
                       const int* __restrict__ deg, const int* __restrict__ adj,
                       const float* __restrict__ dis, const float* __restrict__ b1,
                       float* __restrict__ h, int n) {
    int node = blockIdx.x * 4 + (threadIdx.x >> 6);
    if (node >= n) return;
    int lane = threadIdx.x & 63;
    int eg = lane >> 4;        // edge-group 0..3
    int d4 = lane & 15;        // float4 slot within row
    int beg = row_ptr[node];
    int cnt = deg[node] - 1;
    const int* a = adj + beg;
    float4 acc = make_float4(0.f, 0.f, 0.f, 0.f);
    int base = 0;
    for (; base + 8 <= cnt; base += 8) {
        int j0 = a[base + eg];
        int j1 = a[base + 4 + eg];
        float4 v0 = *(const float4*)(hn + (size_t)j0 * HID + d4 * 4);
        float4 v1 = *(const float4*)(hn + (size_t)j1 * HID + d4 * 4);
        acc.x += v0.x + v1.x; acc.y += v0.y + v1.y;
        acc.z += v0.z + v1.z; acc.w += v0.w + v1.w;
    }
    int kk = base + eg;
    if (kk < cnt) {
        float4 v = *(const float4*)(hn + (size_t)a[kk] * HID + d4 * 4);
        acc.x += v.x; acc.y += v.y; acc.z += v.z; acc.w += v.w;
    }
    kk += 4;
    if (kk < cnt) {
        float4 v = *(const float4*)(hn + (size_t)a[kk] * HID + d4 * 4);
        acc.x += v.x; acc.y += v.y; acc.z += v.z; acc.w += v.w;
    }
    float4 t = shfl_xor_f4(acc, 16);
    acc.x += t.x; acc.y += t.y; acc.z += t.z; acc.w += t.w;
    t = shfl_xor_f4(acc, 32);
    acc.x += t.x; acc.y += t.y; acc.z += t.z; acc.w += t.w;
    if (eg == 0) {
        float4 self = *(const float4*)(hn + (size_t)node * HID + d4 * 4);
        float4 bb = *(const float4*)(b1 + d4 * 4);
        float dn = dis[node];
        float4 o;
        o.x = fmaxf(dn * (acc.x + self.x) + bb.x, 0.f);
        o.y = fmaxf(dn * (acc.y + self.y) + bb.y, 0.f);
        o.z = fmaxf(dn * (acc.z + self.z) + bb.z, 0.f);
        o.w = fmaxf(dn * (acc.w + self.w) + bb.w, 0.f);
        *(float4*)(h + (size_t)node * HID + d4 * 4) = o;
    }
}

__global__ void k_agg2(const float* __restrict__ hn2, const int* __restrict__ row_ptr,
                       const int* __restrict__ deg, const int* __restrict__ adj,
                       const float* __restrict__ dis, const float* __restrict__ b2,
                       float* __restrict__ z, int n) {
    int node = blockIdx.x * 4 + (threadIdx.x >> 6);
    if (node >= n) return;
    int lane = threadIdx.x & 63;
    int eg = lane >> 3;        // edge-group 0..7
    int d4 = lane & 7;         // float4 slot within row
    int beg = row_ptr[node];
    int cnt = deg[node] - 1;
    const int* a = adj + beg;
    float4 acc = make_float4(0.f, 0.f, 0.f, 0.f);
    int base = 0;
    for (; base + 16 <= cnt; base += 16) {
        int j0 = a[base + eg];
        int j1 = a[base + 8 + eg];
        float4 v0 = *(const float4*)(hn2 + (size_t)j0 * EMB + d4 * 4);
        float4 v1 = *(const float4*)(hn2 + (size_t)j1 * EMB + d4 * 4);
        acc.x += v0.x + v1.x; acc.y += v0.y + v1.y;
        acc.z += v0.z + v1.z; acc.w += v0.w + v1.w;
    }
    int kk = base + eg;
    if (kk < cnt) {
        float4 v = *(const float4*)(hn2 + (size_t)a[kk] * EMB + d4 * 4);
        acc.x += v.x; acc.y += v.y; acc.z += v.z; acc.w += v.w;
    }
    kk += 8;
    if (kk < cnt) {
        float4 v = *(const float4*)(hn2 + (size_t)a[kk] * EMB + d4 * 4);
        acc.x += v.x; acc.y += v.y; acc.z += v.z; acc.w += v.w;
    }
    float4 t = shfl_xor_f4(acc, 8);
    acc.x += t.x; acc.y += t.y; acc.z += t.z; acc.w += t.w;
    t = shfl_xor_f4(acc, 16);
    acc.x += t.x; acc.y += t.y; acc.z += t.z; acc.w += t.w;
    t = shfl_xor_f4(acc, 32);
    acc.x += t.x; acc.y += t.y; acc.z += t.z; acc.w += t.w;
    if (eg == 0) {
        float4 self = *(const float4*)(hn2 + (size_t)node * EMB + d4 * 4);
        float4 bb = *(const float4*)(b2 + d4 * 4);
        float dn = dis[node];
        float4 o;
        o.x = dn * (acc.x + self.x) + bb.x;
        o.y = dn * (acc.y + self.y) + bb.y;
        o.z = dn * (acc.z + self.z) + bb.z;
        o.w = dn * (acc.w + self.w) + bb.w;
        *(float4*)(z + (size_t)node * EMB + d4 * 4) = o;
    }
}

// ---------------- pair head ----------------

__global__ void k_head(const float* __restrict__ z, const int* __restrict__ tg,
                       const float* __restrict__ Wo, const float* __restrict__ bo,
                       float* __restrict__ out, int btot) {
    int i = blockIdx.x * 256 + threadIdx.x;
    if (i >= btot) return;
    int t0 = tg[i], t1 = tg[btot + i];
    const float* z0 = z + (size_t)t0 * EMB;
    const float* z1 = z + (size_t)t1 * EMB;
    float acc = 0.f;
#pragma unroll
    for (int g = 0; g < EMB; ++g) acc += z0[g] * z1[g] * Wo[g];
    out[i] = acc + bo[0];
}

// ---------------- launch ----------------

extern "C" void kernel_launch(void* const* d_in, const int* in_sizes, int n_in,
                              void* d_out, int out_size, void* d_ws, size_t ws_size,
                              hipStream_t stream) {
    const float* x  = (const float*)d_in[0];
    const int*   ei = (const int*)d_in[1];
    const int*   tg = (const int*)d_in[2];
    const float* W1 = (const float*)d_in[3];
    const float* b1 = (const float*)d_in[4];
    const float* W2 = (const float*)d_in[5];
    const float* b2 = (const float*)d_in[6];
    const float* Wo = (const float*)d_in[7];
    const float* bo = (const float*)d_in[8];
    float* out = (float*)d_out;

    int n = in_sizes[0] / IN_DIM;
    int e = in_sizes[1] / 2;
    int b = in_sizes[2] / 2;
    const int* src = ei;
    const int* dst = ei + e;

    char* ws = (char*)d_ws;
    size_t off = 0;
    auto alloc = [&](size_t bytes) -> char* {
        char* p = ws + off;
        off += (bytes + 255) & ~(size_t)255;
        return p;
    };
    int*   deg       = (int*)alloc((size_t)n * 4);
    int*   row_ptr   = (int*)alloc((size_t)n * 4);
    int*   write_ptr = (int*)alloc((size_t)n * 4);
    int*   blksums   = (int*)alloc(1024 * 4);
    int*   blkoffs   = (int*)alloc(1024 * 4);
    float* dis       = (float*)alloc((size_t)n * 4);
    int*   adj       = (int*)alloc((size_t)e * 4);
    float* bufA      = (float*)alloc((size_t)n * HID * 4);  // hn, then hn2
    float* bufB      = (float*)alloc((size_t)n * HID * 4);  // h,  then z
    int*   gcnt      = (int*)alloc(256);
    int    cap       = e / NGROUP + e / (NGROUP * 4) + 1024; // mean + 25% headroom
    size_t bucket_bytes = (size_t)NGROUP * cap * 8;
    bool   use_buckets = (off + bucket_bytes + 256) <= ws_size;
    u64*   gbuf      = (u64*)alloc(bucket_bytes);

    int nb1024 = (n + 1023) / 1024;
    int nrange = (n + NGROUP - 1) / NGROUP;
    int part_grid = 2048;

    k_init<<<(n + 255) / 256, 256, 0, stream>>>(deg, gcnt, n);

    if (use_buckets) {
        k_part<<<1024, 256, 0, stream>>>(src, dst, gcnt, gbuf, e, nrange, cap);
        k_count_b<<<1024, 256, 0, stream>>>(gbuf, gcnt, deg, cap);
    } else {
        k_count_part<<<part_grid, 256, 0, stream>>>(dst, deg, e, nrange, n);
    }

    k_dis<<<(n + 255) / 256, 256, 0, stream>>>(deg, dis, n);

    k_scanA<<<nb1024, 1024, 0, stream>>>(deg, row_ptr, blksums, n);
    k_scanB<<<1, 1024, 0, stream>>>(blksums, blkoffs, nb1024);
    k_scanC<<<nb1024, 1024, 0, stream>>>(row_ptr, blkoffs, write_ptr, n);

    if (use_buckets) {
        k_fill_b<<<1024, 256, 0, stream>>>(gbuf, gcnt, write_ptr, adj, cap);
    } else {
        k_fill_part<<<part_grid, 256, 0, stream>>>(src, dst, write_ptr, adj, e, nrange, n);
    }

    k_gemm1<<<((size_t)n * HID + 255) / 256, 256, 0, stream>>>(x, W1, dis, bufA, n);
    k_agg1<<<(n + 3) / 4, 256, 0, stream>>>(bufA, row_ptr, deg, adj, dis, b1, bufB, n);
    k_gemm2<<<((size_t)n * EMB + 255) / 256, 256, 0, stream>>>(bufB, W2, dis, bufA, n);
    k_agg2<<<(n + 3) / 4, 256, 0, stream>>>(bufA, row_ptr, deg, adj, dis, b2, bufB, n);

    k_head<<<(b + 255) / 256, 256, 0, stream>>>(bufB, tg, Wo, bo, out, b);
}

// Round 6
// 329.849 us; speedup vs baseline: 1.6694x; 1.6694x over previous
//
#include <hip/hip_runtime.h>

#define IN_DIM 18
#define HID 64
#define EMB 32
#define NGROUP 8    // legacy fallback partitioning
#define PSHIFT 9    // 512 nodes per partition
#define PMAX 200    // LDS arrays sized for <=200 partitions (N<=102400)
#define BCAP 80     // k_part per-tile LDS bin capacity (mean ~42)
#define TILE 8192
#define SCAP 16896  // k_build LDS pair-staging capacity (mean ~16384)
#define PCAP 336    // legacy

typedef int vint4 __attribute__((ext_vector_type(4)));
typedef unsigned long long u64;

__device__ inline float4 shfl_xor_f4(float4 v, int m) {
    v.x = __shfl_xor(v.x, m);
    v.y = __shfl_xor(v.y, m);
    v.z = __shfl_xor(v.z, m);
    v.w = __shfl_xor(v.w, m);
    return v;
}

// ---------------- init ----------------

__global__ void k_init(int* __restrict__ deg, int* __restrict__ gcnt, int n) {
    int i = blockIdx.x * 256 + threadIdx.x;
    if (i < n) deg[i] = 1;          // self-loop (legacy path)
    if (i < 256) gcnt[i] = 0;
}

// ---------------- bucketing: (dst,src) -> P=196 dst-partition buckets ----------
// pair packed as u64: (src<<32) | dst

__global__ void k_part(const int* __restrict__ src, const int* __restrict__ dst,
                       int* __restrict__ gcnt, u64* __restrict__ gbuf,
                       int e, int Pp, int cap) {
    __shared__ u64 sbuf[PMAX][BCAP];
    __shared__ int scnt[PMAX];
    __shared__ int sbase[PMAX];
    int tid = threadIdx.x;
    int ntile = (e + TILE - 1) / TILE;
    for (int tile = blockIdx.x; tile < ntile; tile += gridDim.x) {
        for (int p = tid; p < Pp; p += 256) scnt[p] = 0;
        __syncthreads();
#pragma unroll
        for (int r = 0; r < TILE / 1024; ++r) {
            int i = tile * TILE + (r * 256 + tid) * 4;
            if (i + 4 <= e) {
                vint4 s4 = __builtin_nontemporal_load((const vint4*)(src + i));
                vint4 d4 = __builtin_nontemporal_load((const vint4*)(dst + i));
#pragma unroll
                for (int k = 0; k < 4; ++k) {
                    int d = d4[k];
                    int p = d >> PSHIFT;
                    u64 pr = ((u64)(unsigned)s4[k] << 32) | (unsigned)d;
                    int pos = atomicAdd(&scnt[p], 1);
                    if (pos < BCAP) sbuf[p][pos] = pr;
                    else {
                        int gp = atomicAdd(&gcnt[p], 1);
                        __builtin_nontemporal_store(pr, &gbuf[(size_t)p * cap + gp]);
                    }
                }
            } else if (i < e) {
                for (int k = i; k < e; ++k) {
                    int d = dst[k];
                    int p = d >> PSHIFT;
                    u64 pr = ((u64)(unsigned)src[k] << 32) | (unsigned)d;
                    int pos = atomicAdd(&scnt[p], 1);
                    if (pos < BCAP) sbuf[p][pos] = pr;
                    else {
                        int gp = atomicAdd(&gcnt[p], 1);
                        __builtin_nontemporal_store(pr, &gbuf[(size_t)p * cap + gp]);
                    }
                }
            }
        }
        __syncthreads();
        for (int p = tid; p < Pp; p += 256)
            sbase[p] = atomicAdd(&gcnt[p], min(scnt[p], BCAP));
        __syncthreads();
        int wid = tid >> 6, lane = tid & 63;
        for (int p = wid; p < Pp; p += 4) {
            int c = min(scnt[p], BCAP);
            int b = sbase[p];
            for (int k = lane; k < c; k += 64)
                __builtin_nontemporal_store(sbuf[p][k], &gbuf[(size_t)p * cap + b + k]);
        }
        __syncthreads();
    }
}

// ---------------- tiny exclusive scan of bucket counts ----------------

__global__ void k_gscan(const int* __restrict__ gcnt, int* __restrict__ gbase, int Pp) {
    __shared__ int s[256];
    int t = threadIdx.x;
    int v = (t < Pp) ? gcnt[t] : 0;
    s[t] = v;
    __syncthreads();
    for (int off = 1; off < 256; off <<= 1) {
        int u = (t >= off) ? s[t - off] : 0;
        __syncthreads();
        s[t] += u;
        __syncthreads();
    }
    if (t < Pp) gbase[t] = s[t] - v;
}

// ---------------- per-partition build: deg/dis/row_ptr/adj in one kernel ------
// One block per partition: all scatter targets owned by ONE CU/XCD -> L2 merge.

__global__ void k_build(const u64* __restrict__ gbuf, const int* __restrict__ gcnt,
                        const int* __restrict__ gbase, int* __restrict__ deg,
                        float* __restrict__ dis, int* __restrict__ row_ptr,
                        int* __restrict__ adj, int cap, int n) {
    __shared__ u64 spairs[SCAP];
    __shared__ int sdeg[512];
    __shared__ int sexcl[512];
    __shared__ int swp[512];
    __shared__ int sscan[256];
    int p = blockIdx.x;
    int tid = threadIdx.x;
    int lo = p << PSHIFT;
    int nn = min(n - lo, 512);
    int cnt = gcnt[p];
    int base = gbase[p];
    const u64* buf = gbuf + (size_t)p * cap;

    sdeg[tid] = 0; sdeg[tid + 256] = 0;
    int scap = min(cnt, SCAP);
    for (int k = tid; k < scap; k += 256)
        spairs[k] = __builtin_nontemporal_load(&buf[k]);
    __syncthreads();
    // count
    for (int k = tid; k < cnt; k += 256) {
        u64 pr = (k < SCAP) ? spairs[k] : __builtin_nontemporal_load(&buf[k]);
        atomicAdd(&sdeg[(int)(pr & 0xffffffffu) - lo], 1);
    }
    __syncthreads();
    // exclusive scan over 512 entries (pairwise + Hillis-Steele over 256)
    int e0 = sdeg[2 * tid], e1 = sdeg[2 * tid + 1];
    sscan[tid] = e0 + e1;
    __syncthreads();
    for (int off = 1; off < 256; off <<= 1) {
        int u = (tid >= off) ? sscan[tid - off] : 0;
        __syncthreads();
        sscan[tid] += u;
        __syncthreads();
    }
    int before = (tid > 0) ? sscan[tid - 1] : 0;
    sexcl[2 * tid] = before;
    sexcl[2 * tid + 1] = before + e0;
    swp[tid] = 0; swp[tid + 256] = 0;
    __syncthreads();
    // emit deg/dis/row_ptr (coalesced)
    for (int i = tid; i < nn; i += 256) {
        int dg = sdeg[i] + 1;
        deg[lo + i] = dg;
        dis[lo + i] = rsqrtf((float)dg);
        row_ptr[lo + i] = base + sexcl[i];
    }
    // fill adj (random 4B stores within this block's ~64KB region)
    for (int k = tid; k < cnt; k += 256) {
        u64 pr = (k < SCAP) ? spairs[k] : __builtin_nontemporal_load(&buf[k]);
        int dl = (int)(pr & 0xffffffffu) - lo;
        int slot = sexcl[dl] + atomicAdd(&swp[dl], 1);
        adj[base + slot] = (int)(pr >> 32);
    }
}

// ---------------- legacy fallback (ws too small / too many partitions) --------

__global__ void k_count_part(const int* __restrict__ dst, int* __restrict__ deg,
                             int e, int nrange, int n) {
    int g  = blockIdx.x & (NGROUP - 1);
    int lo = g * nrange;
    int hi = min(n, lo + nrange);
    int bid  = blockIdx.x >> 3;
    int nblk = gridDim.x >> 3;
    int i0   = (bid * 256 + threadIdx.x) * 4;
    int step = nblk * 256 * 4;
    for (int i = i0; i < e; i += step) {
        if (i + 4 <= e) {
            int4 d4 = *(const int4*)(dst + i);
            if (d4.x >= lo && d4.x < hi) atomicAdd(&deg[d4.x], 1);
            if (d4.y >= lo && d4.y < hi) atomicAdd(&deg[d4.y], 1);
            if (d4.z >= lo && d4.z < hi) atomicAdd(&deg[d4.z], 1);
            if (d4.w >= lo && d4.w < hi) atomicAdd(&deg[d4.w], 1);
        } else {
            for (int k = i; k < e; ++k) {
                int d = dst[k];
                if (d >= lo && d < hi) atomicAdd(&deg[d], 1);
            }
        }
    }
}

__global__ void k_dis(const int* __restrict__ deg, float* __restrict__ dis, int n) {
    int i = blockIdx.x * 256 + threadIdx.x;
    if (i < n) dis[i] = rsqrtf((float)deg[i]);
}

__global__ void k_scanA(const int* __restrict__ deg, int* __restrict__ row_ptr,
                        int* __restrict__ blksums, int n) {
    __shared__ int s[1024];
    int tid = threadIdx.x;
    int i = blockIdx.x * 1024 + tid;
    int v = (i < n) ? (deg[i] - 1) : 0;
    s[tid] = v;
    __syncthreads();
    for (int off = 1; off < 1024; off <<= 1) {
        int t = (tid >= off) ? s[tid - off] : 0;
        __syncthreads();
        s[tid] += t;
        __syncthreads();
    }
    if (i < n) row_ptr[i] = s[tid] - v;
    if (tid == 1023) blksums[blockIdx.x] = s[1023];
}

__global__ void k_scanB(const int* __restrict__ blksums, int* __restrict__ blkoffs, int nb) {
    __shared__ int s[1024];
    int tid = threadIdx.x;
    int v = (tid < nb) ? blksums[tid] : 0;
    s[tid] = v;
    __syncthreads();
    for (int off = 1; off < 1024; off <<= 1) {
        int t = (tid >= off) ? s[tid - off] : 0;
        __syncthreads();
        s[tid] += t;
        __syncthreads();
    }
    if (tid < nb) blkoffs[tid] = s[tid] - v;
}

__global__ void k_scanC(int* __restrict__ row_ptr, const int* __restrict__ blkoffs,
                        int* __restrict__ write_ptr, int n) {
    int i = blockIdx.x * 1024 + threadIdx.x;
    if (i < n) {
        int r = row_ptr[i] + blkoffs[blockIdx.x];
        row_ptr[i] = r;
        write_ptr[i] = r;
    }
}

__global__ void k_fill_part(const int* __restrict__ src, const int* __restrict__ dst,
                            int* __restrict__ write_ptr, int* __restrict__ adj,
                            int e, int nrange, int n) {
    int g  = blockIdx.x & (NGROUP - 1);
    int lo = g * nrange;
    int hi = min(n, lo + nrange);
    int bid  = blockIdx.x >> 3;
    int nblk = gridDim.x >> 3;
    int i0   = (bid * 256 + threadIdx.x) * 4;
    int step = nblk * 256 * 4;
    for (int i = i0; i < e; i += step) {
        if (i + 4 <= e) {
            int4 d4 = *(const int4*)(dst + i);
            if (d4.x >= lo && d4.x < hi) { int slot = atomicAdd(&write_ptr[d4.x], 1); adj[slot] = src[i];     }
            if (d4.y >= lo && d4.y < hi) { int slot = atomicAdd(&write_ptr[d4.y], 1); adj[slot] = src[i + 1]; }
            if (d4.z >= lo && d4.z < hi) { int slot = atomicAdd(&write_ptr[d4.z], 1); adj[slot] = src[i + 2]; }
            if (d4.w >= lo && d4.w < hi) { int slot = atomicAdd(&write_ptr[d4.w], 1); adj[slot] = src[i + 3]; }
        } else {
            for (int k = i; k < e; ++k) {
                int d = dst[k];
                if (d >= lo && d < hi) { int slot = atomicAdd(&write_ptr[d], 1); adj[slot] = src[k]; }
            }
        }
    }
}

// ---------------- layer GEMMs (dense, tiny K) ----------------

__global__ void k_gemm1(const float* __restrict__ x, const float* __restrict__ W1,
                        const float* __restrict__ dis, float* __restrict__ hn, int n) {
    __shared__ float w[IN_DIM * HID];
    for (int t = threadIdx.x; t < IN_DIM * HID; t += 256) w[t] = W1[t];
    __syncthreads();
    int gid = blockIdx.x * 256 + threadIdx.x;
    int i = gid >> 6, f = gid & 63;
    if (i >= n) return;
    const float* xr = x + (size_t)i * IN_DIM;
    float acc = 0.f;
#pragma unroll
    for (int k = 0; k < IN_DIM; ++k) acc += xr[k] * w[k * HID + f];
    hn[(size_t)i * HID + f] = acc * dis[i];
}

__global__ void k_gemm2(const float* __restrict__ h, const float* __restrict__ W2,
                        const float* __restrict__ dis, float* __restrict__ hn2, int n) {
    __shared__ float w[HID * EMB];
    for (int t = threadIdx.x; t < HID * EMB; t += 256) w[t] = W2[t];
    __syncthreads();
    int gid = blockIdx.x * 256 + threadIdx.x;
    int i = gid >> 5, g = gid & 31;
    if (i >= n) return;
    const float* hr = h + (size_t)i * HID;
    float acc = 0.f;
#pragma unroll
    for (int k = 0; k < HID; ++k) acc += hr[k] * w[k * EMB + g];
    hn2[(size_t)i * EMB + g] = acc * dis[i];
}

// ---------------- aggregation (gather over CSR, float4 per lane) ----------------

__global__ void k_agg1(const float* __restrict__ hn, const int* __restrict__ row_ptr,
                       const int* __restrict__ deg, const int* __restrict__ adj,
                       const float* __restrict__ dis, const float* __restrict__ b1,
                       float* __restrict__ h, int n) {
    int node = blockIdx.x * 4 + (threadIdx.x >> 6);
    if (node >= n) return;
    int lane = threadIdx.x & 63;
    int eg = lane >> 4;
    int d4 = lane & 15;
    int beg = row_ptr[node];
    int cnt = deg[node] - 1;
    const int* a = adj + beg;
    float4 acc = make_float4(0.f, 0.f, 0.f, 0.f);
    int base = 0;
    for (; base + 8 <= cnt; base += 8) {
        int j0 = a[base + eg];
        int j1 = a[base + 4 + eg];
        float4 v0 = *(const float4*)(hn + (size_t)j0 * HID + d4 * 4);
        float4 v1 = *(const float4*)(hn + (size_t)j1 * HID + d4 * 4);
        acc.x += v0.x + v1.x; acc.y += v0.y + v1.y;
        acc.z += v0.z + v1.z; acc.w += v0.w + v1.w;
    }
    int kk = base + eg;
    if (kk < cnt) {
        float4 v = *(const float4*)(hn + (size_t)a[kk] * HID + d4 * 4);
        acc.x += v.x; acc.y += v.y; acc.z += v.z; acc.w += v.w;
    }
    kk += 4;
    if (kk < cnt) {
        float4 v = *(const float4*)(hn + (size_t)a[kk] * HID + d4 * 4);
        acc.x += v.x; acc.y += v.y; acc.z += v.z; acc.w += v.w;
    }
    float4 t = shfl_xor_f4(acc, 16);
    acc.x += t.x; acc.y += t.y; acc.z += t.z; acc.w += t.w;
    t = shfl_xor_f4(acc, 32);
    acc.x += t.x; acc.y += t.y; acc.z += t.z; acc.w += t.w;
    if (eg == 0) {
        float4 self = *(const float4*)(hn + (size_t)node * HID + d4 * 4);
        float4 bb = *(const float4*)(b1 + d4 * 4);
        float dn = dis[node];
        float4 o;
        o.x = fmaxf(dn * (acc.x + self.x) + bb.x, 0.f);
        o.y = fmaxf(dn * (acc.y + self.y) + bb.y, 0.f);
        o.z = fmaxf(dn * (acc.z + self.z) + bb.z, 0.f);
        o.w = fmaxf(dn * (acc.w + self.w) + bb.w, 0.f);
        *(float4*)(h + (size_t)node * HID + d4 * 4) = o;
    }
}

__global__ void k_agg2(const float* __restrict__ hn2, const int* __restrict__ row_ptr,
                       const int* __restrict__ deg, const int* __restrict__ adj,
                       const float* __restrict__ dis, const float* __restrict__ b2,
                       float* __restrict__ z, int n) {
    int node = blockIdx.x * 4 + (threadIdx.x >> 6);
    if (node >= n) return;
    int lane = threadIdx.x & 63;
    int eg = lane >> 3;
    int d4 = lane & 7;
    int beg = row_ptr[node];
    int cnt = deg[node] - 1;
    const int* a = adj + beg;
    float4 acc = make_float4(0.f, 0.f, 0.f, 0.f);
    int base = 0;
    for (; base + 16 <= cnt; base += 16) {
        int j0 = a[base + eg];
        int j1 = a[base + 8 + eg];
        float4 v0 = *(const float4*)(hn2 + (size_t)j0 * EMB + d4 * 4);
        float4 v1 = *(const float4*)(hn2 + (size_t)j1 * EMB + d4 * 4);
        acc.x += v0.x + v1.x; acc.y += v0.y + v1.y;
        acc.z += v0.z + v1.z; acc.w += v0.w + v1.w;
    }
    int kk = base + eg;
    if (kk < cnt) {
        float4 v = *(const float4*)(hn2 + (size_t)a[kk] * EMB + d4 * 4);
        acc.x += v.x; acc.y += v.y; acc.z += v.z; acc.w += v.w;
    }
    kk += 8;
    if (kk < cnt) {
        float4 v = *(const float4*)(hn2 + (size_t)a[kk] * EMB + d4 * 4);
        acc.x += v.x; acc.y += v.y; acc.z += v.z; acc.w += v.w;
    }
    float4 t = shfl_xor_f4(acc, 8);
    acc.x += t.x; acc.y += t.y; acc.z += t.z; acc.w += t.w;
    t = shfl_xor_f4(acc, 16);
    acc.x += t.x; acc.y += t.y; acc.z += t.z; acc.w += t.w;
    t = shfl_xor_f4(acc, 32);
    acc.x += t.x; acc.y += t.y; acc.z += t.z; acc.w += t.w;
    if (eg == 0) {
        float4 self = *(const float4*)(hn2 + (size_t)node * EMB + d4 * 4);
        float4 bb = *(const float4*)(b2 + d4 * 4);
        float dn = dis[node];
        float4 o;
        o.x = dn * (acc.x + self.x) + bb.x;
        o.y = dn * (acc.y + self.y) + bb.y;
        o.z = dn * (acc.z + self.z) + bb.z;
        o.w = dn * (acc.w + self.w) + bb.w;
        *(float4*)(z + (size_t)node * EMB + d4 * 4) = o;
    }
}

// ---------------- pair head ----------------

__global__ void k_head(const float* __restrict__ z, const int* __restrict__ tg,
                       const float* __restrict__ Wo, const float* __restrict__ bo,
                       float* __restrict__ out, int btot) {
    int i = blockIdx.x * 256 + threadIdx.x;
    if (i >= btot) return;
    int t0 = tg[i], t1 = tg[btot + i];
    const float* z0 = z + (size_t)t0 * EMB;
    const float* z1 = z + (size_t)t1 * EMB;
    float acc = 0.f;
#pragma unroll
    for (int g = 0; g < EMB; ++g) acc += z0[g] * z1[g] * Wo[g];
    out[i] = acc + bo[0];
}

// ---------------- launch ----------------

extern "C" void kernel_launch(void* const* d_in, const int* in_sizes, int n_in,
                              void* d_out, int out_size, void* d_ws, size_t ws_size,
                              hipStream_t stream) {
    const float* x  = (const float*)d_in[0];
    const int*   ei = (const int*)d_in[1];
    const int*   tg = (const int*)d_in[2];
    const float* W1 = (const float*)d_in[3];
    const float* b1 = (const float*)d_in[4];
    const float* W2 = (const float*)d_in[5];
    const float* b2 = (const float*)d_in[6];
    const float* Wo = (const float*)d_in[7];
    const float* bo = (const float*)d_in[8];
    float* out = (float*)d_out;

    int n = in_sizes[0] / IN_DIM;
    int e = in_sizes[1] / 2;
    int b = in_sizes[2] / 2;
    const int* src = ei;
    const int* dst = ei + e;

    char* ws = (char*)d_ws;
    size_t off = 0;
    auto alloc = [&](size_t bytes) -> char* {
        char* p = ws + off;
        off += (bytes + 255) & ~(size_t)255;
        return p;
    };
    int*   deg       = (int*)alloc((size_t)n * 4);
    int*   row_ptr   = (int*)alloc((size_t)n * 4);
    int*   write_ptr = (int*)alloc((size_t)n * 4);
    int*   blksums   = (int*)alloc(1024 * 4);
    int*   blkoffs   = (int*)alloc(1024 * 4);
    float* dis       = (float*)alloc((size_t)n * 4);
    int*   adj       = (int*)alloc((size_t)e * 4);
    float* bufA      = (float*)alloc((size_t)n * HID * 4);
    float* bufB      = (float*)alloc((size_t)n * HID * 4);
    int*   gcnt      = (int*)alloc(1024);
    int*   gbase     = (int*)alloc(1024);

    int Pp = (n + 511) >> PSHIFT;                    // partitions (196 for N=100K)
    int meanb = (Pp > 0) ? (e / Pp) : e;
    int cap = meanb + meanb / 16 + 1024;             // ~8 sigma headroom
    size_t bucket_bytes = (size_t)Pp * cap * 8;
    bool use_buckets = (Pp <= PMAX) && ((off + bucket_bytes + 256) <= ws_size);
    u64* gbuf = (u64*)alloc(bucket_bytes);

    int nb1024 = (n + 1023) / 1024;
    int nrange = (n + NGROUP - 1) / NGROUP;

    k_init<<<(n + 255) / 256, 256, 0, stream>>>(deg, gcnt, n);

    if (use_buckets) {
        k_part<<<256, 256, 0, stream>>>(src, dst, gcnt, gbuf, e, Pp, cap);
        k_gscan<<<1, 256, 0, stream>>>(gcnt, gbase, Pp);
        k_build<<<Pp, 256, 0, stream>>>(gbuf, gcnt, gbase, deg, dis, row_ptr, adj, cap, n);
    } else {
        k_count_part<<<2048, 256, 0, stream>>>(dst, deg, e, nrange, n);
        k_dis<<<(n + 255) / 256, 256, 0, stream>>>(deg, dis, n);
        k_scanA<<<nb1024, 1024, 0, stream>>>(deg, row_ptr, blksums, n);
        k_scanB<<<1, 1024, 0, stream>>>(blksums, blkoffs, nb1024);
        k_scanC<<<nb1024, 1024, 0, stream>>>(row_ptr, blkoffs, write_ptr, n);
        k_fill_part<<<2048, 256, 0, stream>>>(src, dst, write_ptr, adj, e, nrange, n);
    }

    k_gemm1<<<((size_t)n * HID + 255) / 256, 256, 0, stream>>>(x, W1, dis, bufA, n);
    k_agg1<<<(n + 3) / 4, 256, 0, stream>>>(bufA, row_ptr, deg, adj, dis, b1, bufB, n);
    k_gemm2<<<((size_t)n * EMB + 255) / 256, 256, 0, stream>>>(bufB, W2, dis, bufA, n);
    k_agg2<<<(n + 3) / 4, 256, 0, stream>>>(bufA, row_ptr, deg, adj, dis, b2, bufB, n);

    k_head<<<(b + 255) / 256, 256, 0, stream>>>(bufB, tg, Wo, bo, out, b);
}

// Round 7
// 270.283 us; speedup vs baseline: 2.0373x; 1.2204x over previous
//
#include <hip/hip_runtime.h>

#define IN_DIM 18
#define XPAD 20     // IN_DIM padded to float4 multiple (5 slots)
#define HID 64
#define EMB 32
#define NGROUP 8    // legacy fallback partitioning
#define PSHIFT 9    // 512 nodes per partition
#define PMAX 200    // LDS arrays sized for <=200 partitions (N<=102400)
#define BCAP 80     // k_part per-tile LDS bin capacity (mean ~42)
#define TILE 8192
#define SCAP 16896  // k_build LDS pair-staging capacity (mean ~16384)

typedef int vint4 __attribute__((ext_vector_type(4)));
typedef unsigned long long u64;

__device__ inline float4 shfl_f4(float4 v, int srcLane) {
    float4 r;
    r.x = __shfl(v.x, srcLane);
    r.y = __shfl(v.y, srcLane);
    r.z = __shfl(v.z, srcLane);
    r.w = __shfl(v.w, srcLane);
    return r;
}

__device__ inline float4 shfl_xor_f4(float4 v, int m) {
    v.x = __shfl_xor(v.x, m);
    v.y = __shfl_xor(v.y, m);
    v.z = __shfl_xor(v.z, m);
    v.w = __shfl_xor(v.w, m);
    return v;
}

// ---------------- init ----------------

__global__ void k_init(int* __restrict__ deg, int* __restrict__ gcnt, int n) {
    int i = blockIdx.x * 256 + threadIdx.x;
    if (i < n) deg[i] = 1;          // self-loop (legacy path)
    if (i < 256) gcnt[i] = 0;
}

// ---------------- bucketing: (dst,src) -> P dst-partition buckets ----------
// pair packed as u64: (src<<32) | dst

__global__ void k_part(const int* __restrict__ src, const int* __restrict__ dst,
                       int* __restrict__ gcnt, u64* __restrict__ gbuf,
                       int e, int Pp, int cap) {
    __shared__ u64 sbuf[PMAX][BCAP];
    __shared__ int scnt[PMAX];
    __shared__ int sbase[PMAX];
    int tid = threadIdx.x;
    int ntile = (e + TILE - 1) / TILE;
    for (int tile = blockIdx.x; tile < ntile; tile += gridDim.x) {
        for (int p = tid; p < Pp; p += 256) scnt[p] = 0;
        __syncthreads();
#pragma unroll
        for (int r = 0; r < TILE / 1024; ++r) {
            int i = tile * TILE + (r * 256 + tid) * 4;
            if (i + 4 <= e) {
                vint4 s4 = __builtin_nontemporal_load((const vint4*)(src + i));
                vint4 d4 = __builtin_nontemporal_load((const vint4*)(dst + i));
#pragma unroll
                for (int k = 0; k < 4; ++k) {
                    int d = d4[k];
                    int p = d >> PSHIFT;
                    u64 pr = ((u64)(unsigned)s4[k] << 32) | (unsigned)d;
                    int pos = atomicAdd(&scnt[p], 1);
                    if (pos < BCAP) sbuf[p][pos] = pr;
                    else {
                        int gp = atomicAdd(&gcnt[p], 1);
                        __builtin_nontemporal_store(pr, &gbuf[(size_t)p * cap + gp]);
                    }
                }
            } else if (i < e) {
                for (int k = i; k < e; ++k) {
                    int d = dst[k];
                    int p = d >> PSHIFT;
                    u64 pr = ((u64)(unsigned)src[k] << 32) | (unsigned)d;
                    int pos = atomicAdd(&scnt[p], 1);
                    if (pos < BCAP) sbuf[p][pos] = pr;
                    else {
                        int gp = atomicAdd(&gcnt[p], 1);
                        __builtin_nontemporal_store(pr, &gbuf[(size_t)p * cap + gp]);
                    }
                }
            }
        }
        __syncthreads();
        for (int p = tid; p < Pp; p += 256)
            sbase[p] = atomicAdd(&gcnt[p], min(scnt[p], BCAP));
        __syncthreads();
        int wid = tid >> 6, lane = tid & 63;
        for (int p = wid; p < Pp; p += 4) {
            int c = min(scnt[p], BCAP);
            int b = sbase[p];
            for (int k = lane; k < c; k += 64)
                __builtin_nontemporal_store(sbuf[p][k], &gbuf[(size_t)p * cap + b + k]);
        }
        __syncthreads();
    }
}

// ---------------- tiny exclusive scan of bucket counts ----------------

__global__ void k_gscan(const int* __restrict__ gcnt, int* __restrict__ gbase, int Pp) {
    __shared__ int s[256];
    int t = threadIdx.x;
    int v = (t < Pp) ? gcnt[t] : 0;
    s[t] = v;
    __syncthreads();
    for (int off = 1; off < 256; off <<= 1) {
        int u = (t >= off) ? s[t - off] : 0;
        __syncthreads();
        s[t] += u;
        __syncthreads();
    }
    if (t < Pp) gbase[t] = s[t] - v;
}

// ---------------- per-partition build: deg/dis/row_ptr/adj ----------------

__global__ void k_build(const u64* __restrict__ gbuf, const int* __restrict__ gcnt,
                        const int* __restrict__ gbase, int* __restrict__ deg,
                        float* __restrict__ dis, int* __restrict__ row_ptr,
                        int* __restrict__ adj, int cap, int n) {
    __shared__ u64 spairs[SCAP];
    __shared__ int sdeg[512];
    __shared__ int sexcl[512];
    __shared__ int swp[512];
    __shared__ int sscan[256];
    int p = blockIdx.x;
    int tid = threadIdx.x;
    int lo = p << PSHIFT;
    int nn = min(n - lo, 512);
    int cnt = gcnt[p];
    int base = gbase[p];
    const u64* buf = gbuf + (size_t)p * cap;

    sdeg[tid] = 0; sdeg[tid + 256] = 0;
    int scap = min(cnt, SCAP);
    for (int k = tid; k < scap; k += 256)
        spairs[k] = __builtin_nontemporal_load(&buf[k]);
    __syncthreads();
    for (int k = tid; k < cnt; k += 256) {
        u64 pr = (k < SCAP) ? spairs[k] : __builtin_nontemporal_load(&buf[k]);
        atomicAdd(&sdeg[(int)(pr & 0xffffffffu) - lo], 1);
    }
    __syncthreads();
    int e0 = sdeg[2 * tid], e1 = sdeg[2 * tid + 1];
    sscan[tid] = e0 + e1;
    __syncthreads();
    for (int off = 1; off < 256; off <<= 1) {
        int u = (tid >= off) ? sscan[tid - off] : 0;
        __syncthreads();
        sscan[tid] += u;
        __syncthreads();
    }
    int before = (tid > 0) ? sscan[tid - 1] : 0;
    sexcl[2 * tid] = before;
    sexcl[2 * tid + 1] = before + e0;
    swp[tid] = 0; swp[tid + 256] = 0;
    __syncthreads();
    for (int i = tid; i < nn; i += 256) {
        int dg = sdeg[i] + 1;
        deg[lo + i] = dg;
        dis[lo + i] = rsqrtf((float)dg);
        row_ptr[lo + i] = base + sexcl[i];
    }
    for (int k = tid; k < cnt; k += 256) {
        u64 pr = (k < SCAP) ? spairs[k] : __builtin_nontemporal_load(&buf[k]);
        int dl = (int)(pr & 0xffffffffu) - lo;
        int slot = sexcl[dl] + atomicAdd(&swp[dl], 1);
        adj[base + slot] = (int)(pr >> 32);
    }
}

// ---------------- legacy fallback ----------------

__global__ void k_count_part(const int* __restrict__ dst, int* __restrict__ deg,
                             int e, int nrange, int n) {
    int g  = blockIdx.x & (NGROUP - 1);
    int lo = g * nrange;
    int hi = min(n, lo + nrange);
    int bid  = blockIdx.x >> 3;
    int nblk = gridDim.x >> 3;
    int i0   = (bid * 256 + threadIdx.x) * 4;
    int step = nblk * 256 * 4;
    for (int i = i0; i < e; i += step) {
        if (i + 4 <= e) {
            int4 d4 = *(const int4*)(dst + i);
            if (d4.x >= lo && d4.x < hi) atomicAdd(&deg[d4.x], 1);
            if (d4.y >= lo && d4.y < hi) atomicAdd(&deg[d4.y], 1);
            if (d4.z >= lo && d4.z < hi) atomicAdd(&deg[d4.z], 1);
            if (d4.w >= lo && d4.w < hi) atomicAdd(&deg[d4.w], 1);
        } else {
            for (int k = i; k < e; ++k) {
                int d = dst[k];
                if (d >= lo && d < hi) atomicAdd(&deg[d], 1);
            }
        }
    }
}

__global__ void k_dis(const int* __restrict__ deg, float* __restrict__ dis, int n) {
    int i = blockIdx.x * 256 + threadIdx.x;
    if (i < n) dis[i] = rsqrtf((float)deg[i]);
}

__global__ void k_scanA(const int* __restrict__ deg, int* __restrict__ row_ptr,
                        int* __restrict__ blksums, int n) {
    __shared__ int s[1024];
    int tid = threadIdx.x;
    int i = blockIdx.x * 1024 + tid;
    int v = (i < n) ? (deg[i] - 1) : 0;
    s[tid] = v;
    __syncthreads();
    for (int off = 1; off < 1024; off <<= 1) {
        int t = (tid >= off) ? s[tid - off] : 0;
        __syncthreads();
        s[tid] += t;
        __syncthreads();
    }
    if (i < n) row_ptr[i] = s[tid] - v;
    if (tid == 1023) blksums[blockIdx.x] = s[1023];
}

__global__ void k_scanB(const int* __restrict__ blksums, int* __restrict__ blkoffs, int nb) {
    __shared__ int s[1024];
    int tid = threadIdx.x;
    int v = (tid < nb) ? blksums[tid] : 0;
    s[tid] = v;
    __syncthreads();
    for (int off = 1; off < 1024; off <<= 1) {
        int t = (tid >= off) ? s[tid - off] : 0;
        __syncthreads();
        s[tid] += t;
        __syncthreads();
    }
    if (tid < nb) blkoffs[tid] = s[tid] - v;
}

__global__ void k_scanC(int* __restrict__ row_ptr, const int* __restrict__ blkoffs,
                        int* __restrict__ write_ptr, int n) {
    int i = blockIdx.x * 1024 + threadIdx.x;
    if (i < n) {
        int r = row_ptr[i] + blkoffs[blockIdx.x];
        row_ptr[i] = r;
        write_ptr[i] = r;
    }
}

__global__ void k_fill_part(const int* __restrict__ src, const int* __restrict__ dst,
                            int* __restrict__ write_ptr, int* __restrict__ adj,
                            int e, int nrange, int n) {
    int g  = blockIdx.x & (NGROUP - 1);
    int lo = g * nrange;
    int hi = min(n, lo + nrange);
    int bid  = blockIdx.x >> 3;
    int nblk = gridDim.x >> 3;
    int i0   = (bid * 256 + threadIdx.x) * 4;
    int step = nblk * 256 * 4;
    for (int i = i0; i < e; i += step) {
        if (i + 4 <= e) {
            int4 d4 = *(const int4*)(dst + i);
            if (d4.x >= lo && d4.x < hi) { int slot = atomicAdd(&write_ptr[d4.x], 1); adj[slot] = src[i];     }
            if (d4.y >= lo && d4.y < hi) { int slot = atomicAdd(&write_ptr[d4.y], 1); adj[slot] = src[i + 1]; }
            if (d4.z >= lo && d4.z < hi) { int slot = atomicAdd(&write_ptr[d4.z], 1); adj[slot] = src[i + 2]; }
            if (d4.w >= lo && d4.w < hi) { int slot = atomicAdd(&write_ptr[d4.w], 1); adj[slot] = src[i + 3]; }
        } else {
            for (int k = i; k < e; ++k) {
                int d = dst[k];
                if (d >= lo && d < hi) { int slot = atomicAdd(&write_ptr[d], 1); adj[slot] = src[k]; }
            }
        }
    }
}

// ---------------- xn = x * dis, padded to 20 floats ----------------

__global__ void k_xn(const float* __restrict__ x, const float* __restrict__ dis,
                     float* __restrict__ xn, int n) {
    int gid = blockIdx.x * 256 + threadIdx.x;
    if (gid >= n * 5) return;
    int i = gid / 5, s = gid - (gid / 5) * 5;
    float dn = dis[i];
    const float* xr = x + (size_t)i * IN_DIM;
    float4 v;
    int k = s * 4;
    v.x = (k + 0 < IN_DIM) ? xr[k + 0] * dn : 0.f;
    v.y = (k + 1 < IN_DIM) ? xr[k + 1] * dn : 0.f;
    v.z = (k + 2 < IN_DIM) ? xr[k + 2] * dn : 0.f;
    v.w = (k + 3 < IN_DIM) ? xr[k + 3] * dn : 0.f;
    *(float4*)(xn + (size_t)i * XPAD + k) = v;
}

// ---------------- fused layer-1: gather xn rows + W1 GEMM + bias + relu -------
// One wave per node. 12 edge-groups x 5 lanes x float4 (20-float rows), x2
// unroll -> 24 gathers in flight. 4-step shuffle tree 12->6->3->1, then LDS
// broadcast of the 20-float aggregated row, per-lane W1 dot (K=18), relu.

__global__ void k_agg1f(const float* __restrict__ xn, const int* __restrict__ row_ptr,
                        const int* __restrict__ deg, const int* __restrict__ adj,
                        const float* __restrict__ dis, const float* __restrict__ W1,
                        const float* __restrict__ b1, float* __restrict__ h, int n) {
    __shared__ float sw[IN_DIM * HID];
    __shared__ float sb[HID];
    __shared__ __align__(16) float sagg[4][XPAD];
    int tid = threadIdx.x;
    for (int t = tid; t < IN_DIM * HID; t += 256) sw[t] = W1[t];
    if (tid < HID) sb[tid] = b1[tid];
    __syncthreads();
    int node = blockIdx.x * 4 + (tid >> 6);
    if (node >= n) return;
    int lane = tid & 63;
    int wv = tid >> 6;
    int eg = lane / 5;               // 0..12 (lanes 60-63 -> 12, inactive)
    int sl = lane - eg * 5;          // float4 slot 0..4
    bool act = eg < 12;
    int beg = row_ptr[node];
    int cnt = deg[node] - 1;
    const int* a = adj + beg;
    float4 acc = make_float4(0.f, 0.f, 0.f, 0.f);
    int base = 0;
    for (; base + 24 <= cnt; base += 24) {
        if (act) {
            int j0 = a[base + eg];
            int j1 = a[base + 12 + eg];
            float4 v0 = *(const float4*)(xn + (size_t)j0 * XPAD + sl * 4);
            float4 v1 = *(const float4*)(xn + (size_t)j1 * XPAD + sl * 4);
            acc.x += v0.x + v1.x; acc.y += v0.y + v1.y;
            acc.z += v0.z + v1.z; acc.w += v0.w + v1.w;
        }
    }
    if (act && base + eg < cnt) {
        float4 v = *(const float4*)(xn + (size_t)a[base + eg] * XPAD + sl * 4);
        acc.x += v.x; acc.y += v.y; acc.z += v.z; acc.w += v.w;
    }
    if (act && base + 12 + eg < cnt) {
        float4 v = *(const float4*)(xn + (size_t)a[base + 12 + eg] * XPAD + sl * 4);
        acc.x += v.x; acc.y += v.y; acc.z += v.z; acc.w += v.w;
    }
    // reduce 12 groups -> group 0 (predicated adds; shfl src wraps are unused)
    float4 t = shfl_f4(acc, lane + 30);
    if (lane < 30) { acc.x += t.x; acc.y += t.y; acc.z += t.z; acc.w += t.w; }
    t = shfl_f4(acc, lane + 15);
    if (lane < 15) { acc.x += t.x; acc.y += t.y; acc.z += t.z; acc.w += t.w; }
    t = shfl_f4(acc, lane + 10);
    if (lane < 5) { acc.x += t.x; acc.y += t.y; acc.z += t.z; acc.w += t.w; }
    t = shfl_f4(acc, lane + 5);
    if (lane < 5) { acc.x += t.x; acc.y += t.y; acc.z += t.z; acc.w += t.w; }
    if (lane < 5) {
        float4 s4v = *(const float4*)(xn + (size_t)node * XPAD + lane * 4);
        acc.x += s4v.x; acc.y += s4v.y; acc.z += s4v.z; acc.w += s4v.w;
        *(float4*)&sagg[wv][lane * 4] = acc;   // same-wave LDS: no barrier needed
    }
    float s = 0.f;
#pragma unroll
    for (int k = 0; k < IN_DIM; ++k) s += sagg[wv][k] * sw[k * HID + lane];
    float hv = dis[node] * s + sb[lane];
    h[(size_t)node * HID + lane] = hv > 0.f ? hv : 0.f;
}

// ---------------- layer-2 GEMM ----------------

__global__ void k_gemm2(const float* __restrict__ h, const float* __restrict__ W2,
                        const float* __restrict__ dis, float* __restrict__ hn2, int n) {
    __shared__ float w[HID * EMB];
    for (int t = threadIdx.x; t < HID * EMB; t += 256) w[t] = W2[t];
    __syncthreads();
    int gid = blockIdx.x * 256 + threadIdx.x;
    int i = gid >> 5, g = gid & 31;
    if (i >= n) return;
    const float* hr = h + (size_t)i * HID;
    float acc = 0.f;
#pragma unroll
    for (int k = 0; k < HID; ++k) acc += hr[k] * w[k * EMB + g];
    hn2[(size_t)i * EMB + g] = acc * dis[i];
}

// ---------------- layer-2 aggregation (float4 per lane) ----------------

__global__ void k_agg2(const float* __restrict__ hn2, const int* __restrict__ row_ptr,
                       const int* __restrict__ deg, const int* __restrict__ adj,
                       const float* __restrict__ dis, const float* __restrict__ b2,
                       float* __restrict__ z, int n) {
    int node = blockIdx.x * 4 + (threadIdx.x >> 6);
    if (node >= n) return;
    int lane = threadIdx.x & 63;
    int eg = lane >> 3;
    int d4 = lane & 7;
    int beg = row_ptr[node];
    int cnt = deg[node] - 1;
    const int* a = adj + beg;
    float4 acc = make_float4(0.f, 0.f, 0.f, 0.f);
    int base = 0;
    for (; base + 16 <= cnt; base += 16) {
        int j0 = a[base + eg];
        int j1 = a[base + 8 + eg];
        float4 v0 = *(const float4*)(hn2 + (size_t)j0 * EMB + d4 * 4);
        float4 v1 = *(const float4*)(hn2 + (size_t)j1 * EMB + d4 * 4);
        acc.x += v0.x + v1.x; acc.y += v0.y + v1.y;
        acc.z += v0.z + v1.z; acc.w += v0.w + v1.w;
    }
    int kk = base + eg;
    if (kk < cnt) {
        float4 v = *(const float4*)(hn2 + (size_t)a[kk] * EMB + d4 * 4);
        acc.x += v.x; acc.y += v.y; acc.z += v.z; acc.w += v.w;
    }
    kk += 8;
    if (kk < cnt) {
        float4 v = *(const float4*)(hn2 + (size_t)a[kk] * EMB + d4 * 4);
        acc.x += v.x; acc.y += v.y; acc.z += v.z; acc.w += v.w;
    }
    float4 t = shfl_xor_f4(acc, 8);
    acc.x += t.x; acc.y += t.y; acc.z += t.z; acc.w += t.w;
    t = shfl_xor_f4(acc, 16);
    acc.x += t.x; acc.y += t.y; acc.z += t.z; acc.w += t.w;
    t = shfl_xor_f4(acc, 32);
    acc.x += t.x; acc.y += t.y; acc.z += t.z; acc.w += t.w;
    if (eg == 0) {
        float4 self = *(const float4*)(hn2 + (size_t)node * EMB + d4 * 4);
        float4 bb = *(const float4*)(b2 + d4 * 4);
        float dn = dis[node];
        float4 o;
        o.x = dn * (acc.x + self.x) + bb.x;
        o.y = dn * (acc.y + self.y) + bb.y;
        o.z = dn * (acc.z + self.z) + bb.z;
        o.w = dn * (acc.w + self.w) + bb.w;
        *(float4*)(z + (size_t)node * EMB + d4 * 4) = o;
    }
}

// ---------------- pair head ----------------

__global__ void k_head(const float* __restrict__ z, const int* __restrict__ tg,
                       const float* __restrict__ Wo, const float* __restrict__ bo,
                       float* __restrict__ out, int btot) {
    int i = blockIdx.x * 256 + threadIdx.x;
    if (i >= btot) return;
    int t0 = tg[i], t1 = tg[btot + i];
    const float* z0 = z + (size_t)t0 * EMB;
    const float* z1 = z + (size_t)t1 * EMB;
    float acc = 0.f;
#pragma unroll
    for (int g = 0; g < EMB; ++g) acc += z0[g] * z1[g] * Wo[g];
    out[i] = acc + bo[0];
}

// ---------------- launch ----------------

extern "C" void kernel_launch(void* const* d_in, const int* in_sizes, int n_in,
                              void* d_out, int out_size, void* d_ws, size_t ws_size,
                              hipStream_t stream) {
    const float* x  = (const float*)d_in[0];
    const int*   ei = (const int*)d_in[1];
    const int*   tg = (const int*)d_in[2];
    const float* W1 = (const float*)d_in[3];
    const float* b1 = (const float*)d_in[4];
    const float* W2 = (const float*)d_in[5];
    const float* b2 = (const float*)d_in[6];
    const float* Wo = (const float*)d_in[7];
    const float* bo = (const float*)d_in[8];
    float* out = (float*)d_out;

    int n = in_sizes[0] / IN_DIM;
    int e = in_sizes[1] / 2;
    int b = in_sizes[2] / 2;
    const int* src = ei;
    const int* dst = ei + e;

    char* ws = (char*)d_ws;
    size_t off = 0;
    auto alloc = [&](size_t bytes) -> char* {
        char* p = ws + off;
        off += (bytes + 255) & ~(size_t)255;
        return p;
    };
    int*   deg       = (int*)alloc((size_t)n * 4);
    int*   row_ptr   = (int*)alloc((size_t)n * 4);
    int*   write_ptr = (int*)alloc((size_t)n * 4);
    int*   blksums   = (int*)alloc(1024 * 4);
    int*   blkoffs   = (int*)alloc(1024 * 4);
    float* dis       = (float*)alloc((size_t)n * 4);
    int*   adj       = (int*)alloc((size_t)e * 4);
    float* xn        = (float*)alloc((size_t)n * XPAD * 4);
    float* bufA      = (float*)alloc((size_t)n * EMB * 4);   // hn2
    float* bufB      = (float*)alloc((size_t)n * HID * 4);   // h, then z
    int*   gcnt      = (int*)alloc(1024);
    int*   gbase     = (int*)alloc(1024);

    int Pp = (n + 511) >> PSHIFT;
    int meanb = (Pp > 0) ? (e / Pp) : e;
    int cap = meanb + meanb / 16 + 1024;
    size_t bucket_bytes = (size_t)Pp * cap * 8;
    bool use_buckets = (Pp <= PMAX) && ((off + bucket_bytes + 256) <= ws_size);
    u64* gbuf = (u64*)alloc(bucket_bytes);

    int nb1024 = (n + 1023) / 1024;
    int nrange = (n + NGROUP - 1) / NGROUP;

    k_init<<<(n + 255) / 256, 256, 0, stream>>>(deg, gcnt, n);

    if (use_buckets) {
        k_part<<<256, 256, 0, stream>>>(src, dst, gcnt, gbuf, e, Pp, cap);
        k_gscan<<<1, 256, 0, stream>>>(gcnt, gbase, Pp);
        k_build<<<Pp, 256, 0, stream>>>(gbuf, gcnt, gbase, deg, dis, row_ptr, adj, cap, n);
    } else {
        k_count_part<<<2048, 256, 0, stream>>>(dst, deg, e, nrange, n);
        k_dis<<<(n + 255) / 256, 256, 0, stream>>>(deg, dis, n);
        k_scanA<<<nb1024, 1024, 0, stream>>>(deg, row_ptr, blksums, n);
        k_scanB<<<1, 1024, 0, stream>>>(blksums, blkoffs, nb1024);
        k_scanC<<<nb1024, 1024, 0, stream>>>(row_ptr, blkoffs, write_ptr, n);
        k_fill_part<<<2048, 256, 0, stream>>>(src, dst, write_ptr, adj, e, nrange, n);
    }

    k_xn<<<((size_t)n * 5 + 255) / 256, 256, 0, stream>>>(x, dis, xn, n);
    k_agg1f<<<(n + 3) / 4, 256, 0, stream>>>(xn, row_ptr, deg, adj, dis, W1, b1, bufB, n);
    k_gemm2<<<((size_t)n * EMB + 255) / 256, 256, 0, stream>>>(bufB, W2, dis, bufA, n);
    k_agg2<<<(n + 3) / 4, 256, 0, stream>>>(bufA, row_ptr, deg, adj, dis, b2, bufB, n);

    k_head<<<(b + 255) / 256, 256, 0, stream>>>(bufB, tg, Wo, bo, out, b);
}

// Round 8
// 239.216 us; speedup vs baseline: 2.3019x; 1.1299x over previous
//
#include <hip/hip_runtime.h>

#define IN_DIM 18
#define XPAD 20     // IN_DIM padded to float4 multiple (5 slots)
#define HID 64
#define EMB 32
#define NGROUP 8    // legacy fallback partitioning
#define PSHIFT 9    // 512 nodes per partition
#define PMAX 200    // LDS arrays sized for <=200 partitions (N<=102400)
#define BCAP 40     // k_part per-tile LDS bin capacity (mean ~21 @ TILE 4096)
#define TILE 4096
#define SCAP 16896  // k_build LDS pair-staging capacity (mean ~16384)

typedef int vint4 __attribute__((ext_vector_type(4)));
typedef unsigned long long u64;

__device__ inline float4 shfl_f4(float4 v, int srcLane) {
    float4 r;
    r.x = __shfl(v.x, srcLane);
    r.y = __shfl(v.y, srcLane);
    r.z = __shfl(v.z, srcLane);
    r.w = __shfl(v.w, srcLane);
    return r;
}

__device__ inline float4 shfl_xor_f4(float4 v, int m) {
    v.x = __shfl_xor(v.x, m);
    v.y = __shfl_xor(v.y, m);
    v.z = __shfl_xor(v.z, m);
    v.w = __shfl_xor(v.w, m);
    return v;
}

// ---------------- init ----------------

__global__ void k_init(int* __restrict__ deg, int* __restrict__ gcnt, int n) {
    int i = blockIdx.x * 256 + threadIdx.x;
    if (i < n) deg[i] = 1;          // self-loop (legacy path)
    if (i < 256) gcnt[i] = 0;
}

// ---------------- bucketing: (dst,src) -> P dst-partition buckets ----------
// pair packed as u64: (src<<32) | dst

__global__ void k_part(const int* __restrict__ src, const int* __restrict__ dst,
                       int* __restrict__ gcnt, u64* __restrict__ gbuf,
                       int e, int Pp, int cap) {
    __shared__ u64 sbuf[PMAX][BCAP];
    __shared__ int scnt[PMAX];
    __shared__ int sbase[PMAX];
    int tid = threadIdx.x;
    int ntile = (e + TILE - 1) / TILE;
    for (int tile = blockIdx.x; tile < ntile; tile += gridDim.x) {
        for (int p = tid; p < Pp; p += 256) scnt[p] = 0;
        __syncthreads();
#pragma unroll
        for (int r = 0; r < TILE / 1024; ++r) {
            int i = tile * TILE + (r * 256 + tid) * 4;
            if (i + 4 <= e) {
                vint4 s4 = __builtin_nontemporal_load((const vint4*)(src + i));
                vint4 d4 = __builtin_nontemporal_load((const vint4*)(dst + i));
#pragma unroll
                for (int k = 0; k < 4; ++k) {
                    int d = d4[k];
                    int p = d >> PSHIFT;
                    u64 pr = ((u64)(unsigned)s4[k] << 32) | (unsigned)d;
                    int pos = atomicAdd(&scnt[p], 1);
                    if (pos < BCAP) sbuf[p][pos] = pr;
                    else {
                        int gp = atomicAdd(&gcnt[p], 1);
                        __builtin_nontemporal_store(pr, &gbuf[(size_t)p * cap + gp]);
                    }
                }
            } else if (i < e) {
                for (int k = i; k < e; ++k) {
                    int d = dst[k];
                    int p = d >> PSHIFT;
                    u64 pr = ((u64)(unsigned)src[k] << 32) | (unsigned)d;
                    int pos = atomicAdd(&scnt[p], 1);
                    if (pos < BCAP) sbuf[p][pos] = pr;
                    else {
                        int gp = atomicAdd(&gcnt[p], 1);
                        __builtin_nontemporal_store(pr, &gbuf[(size_t)p * cap + gp]);
                    }
                }
            }
        }
        __syncthreads();
        for (int p = tid; p < Pp; p += 256)
            sbase[p] = atomicAdd(&gcnt[p], min(scnt[p], BCAP));
        __syncthreads();
        int wid = tid >> 6, lane = tid & 63;
        for (int p = wid; p < Pp; p += 4) {
            int c = min(scnt[p], BCAP);
            int b = sbase[p];
            for (int k = lane; k < c; k += 64)
                __builtin_nontemporal_store(sbuf[p][k], &gbuf[(size_t)p * cap + b + k]);
        }
        __syncthreads();
    }
}

// ---------------- tiny exclusive scan of bucket counts ----------------

__global__ void k_gscan(const int* __restrict__ gcnt, int* __restrict__ gbase, int Pp) {
    __shared__ int s[256];
    int t = threadIdx.x;
    int v = (t < Pp) ? gcnt[t] : 0;
    s[t] = v;
    __syncthreads();
    for (int off = 1; off < 256; off <<= 1) {
        int u = (t >= off) ? s[t - off] : 0;
        __syncthreads();
        s[t] += u;
        __syncthreads();
    }
    if (t < Pp) gbase[t] = s[t] - v;
}

// ---------------- per-partition build: deg/dis/row_ptr/adj (512 thr) --------

__global__ void k_build(const u64* __restrict__ gbuf, const int* __restrict__ gcnt,
                        const int* __restrict__ gbase, int* __restrict__ deg,
                        float* __restrict__ dis, int* __restrict__ row_ptr,
                        int* __restrict__ adj, int cap, int n) {
    __shared__ u64 spairs[SCAP];
    __shared__ int sdeg[512];
    __shared__ int sexcl[512];
    __shared__ int swp[512];
    __shared__ int sscan[512];
    int p = blockIdx.x;
    int tid = threadIdx.x;
    int lo = p << PSHIFT;
    int nn = min(n - lo, 512);
    int cnt = gcnt[p];
    int base = gbase[p];
    const u64* buf = gbuf + (size_t)p * cap;

    sdeg[tid] = 0;
    int scap = min(cnt, SCAP);
    for (int k = tid; k < scap; k += 512)
        spairs[k] = __builtin_nontemporal_load(&buf[k]);
    __syncthreads();
    for (int k = tid; k < cnt; k += 512) {
        u64 pr = (k < SCAP) ? spairs[k] : __builtin_nontemporal_load(&buf[k]);
        atomicAdd(&sdeg[(int)(pr & 0xffffffffu) - lo], 1);
    }
    __syncthreads();
    int v = sdeg[tid];
    sscan[tid] = v;
    __syncthreads();
    for (int off = 1; off < 512; off <<= 1) {
        int u = (tid >= off) ? sscan[tid - off] : 0;
        __syncthreads();
        sscan[tid] += u;
        __syncthreads();
    }
    sexcl[tid] = sscan[tid] - v;
    swp[tid] = 0;
    __syncthreads();
    if (tid < nn) {
        int dg = sdeg[tid] + 1;
        deg[lo + tid] = dg;
        dis[lo + tid] = rsqrtf((float)dg);
        row_ptr[lo + tid] = base + sexcl[tid];
    }
    for (int k = tid; k < cnt; k += 512) {
        u64 pr = (k < SCAP) ? spairs[k] : __builtin_nontemporal_load(&buf[k]);
        int dl = (int)(pr & 0xffffffffu) - lo;
        int slot = sexcl[dl] + atomicAdd(&swp[dl], 1);
        adj[base + slot] = (int)(pr >> 32);
    }
}

// ---------------- legacy fallback ----------------

__global__ void k_count_part(const int* __restrict__ dst, int* __restrict__ deg,
                             int e, int nrange, int n) {
    int g  = blockIdx.x & (NGROUP - 1);
    int lo = g * nrange;
    int hi = min(n, lo + nrange);
    int bid  = blockIdx.x >> 3;
    int nblk = gridDim.x >> 3;
    int i0   = (bid * 256 + threadIdx.x) * 4;
    int step = nblk * 256 * 4;
    for (int i = i0; i < e; i += step) {
        if (i + 4 <= e) {
            int4 d4 = *(const int4*)(dst + i);
            if (d4.x >= lo && d4.x < hi) atomicAdd(&deg[d4.x], 1);
            if (d4.y >= lo && d4.y < hi) atomicAdd(&deg[d4.y], 1);
            if (d4.z >= lo && d4.z < hi) atomicAdd(&deg[d4.z], 1);
            if (d4.w >= lo && d4.w < hi) atomicAdd(&deg[d4.w], 1);
        } else {
            for (int k = i; k < e; ++k) {
                int d = dst[k];
                if (d >= lo && d < hi) atomicAdd(&deg[d], 1);
            }
        }
    }
}

__global__ void k_dis(const int* __restrict__ deg, float* __restrict__ dis, int n) {
    int i = blockIdx.x * 256 + threadIdx.x;
    if (i < n) dis[i] = rsqrtf((float)deg[i]);
}

__global__ void k_scanA(const int* __restrict__ deg, int* __restrict__ row_ptr,
                        int* __restrict__ blksums, int n) {
    __shared__ int s[1024];
    int tid = threadIdx.x;
    int i = blockIdx.x * 1024 + tid;
    int v = (i < n) ? (deg[i] - 1) : 0;
    s[tid] = v;
    __syncthreads();
    for (int off = 1; off < 1024; off <<= 1) {
        int t = (tid >= off) ? s[tid - off] : 0;
        __syncthreads();
        s[tid] += t;
        __syncthreads();
    }
    if (i < n) row_ptr[i] = s[tid] - v;
    if (tid == 1023) blksums[blockIdx.x] = s[1023];
}

__global__ void k_scanB(const int* __restrict__ blksums, int* __restrict__ blkoffs, int nb) {
    __shared__ int s[1024];
    int tid = threadIdx.x;
    int v = (tid < nb) ? blksums[tid] : 0;
    s[tid] = v;
    __syncthreads();
    for (int off = 1; off < 1024; off <<= 1) {
        int t = (tid >= off) ? s[tid - off] : 0;
        __syncthreads();
        s[tid] += t;
        __syncthreads();
    }
    if (tid < nb) blkoffs[tid] = s[tid] - v;
}

__global__ void k_scanC(int* __restrict__ row_ptr, const int* __restrict__ blkoffs,
                        int* __restrict__ write_ptr, int n) {
    int i = blockIdx.x * 1024 + threadIdx.x;
    if (i < n) {
        int r = row_ptr[i] + blkoffs[blockIdx.x];
        row_ptr[i] = r;
        write_ptr[i] = r;
    }
}

__global__ void k_fill_part(const int* __restrict__ src, const int* __restrict__ dst,
                            int* __restrict__ write_ptr, int* __restrict__ adj,
                            int e, int nrange, int n) {
    int g  = blockIdx.x & (NGROUP - 1);
    int lo = g * nrange;
    int hi = min(n, lo + nrange);
    int bid  = blockIdx.x >> 3;
    int nblk = gridDim.x >> 3;
    int i0   = (bid * 256 + threadIdx.x) * 4;
    int step = nblk * 256 * 4;
    for (int i = i0; i < e; i += step) {
        if (i + 4 <= e) {
            int4 d4 = *(const int4*)(dst + i);
            if (d4.x >= lo && d4.x < hi) { int slot = atomicAdd(&write_ptr[d4.x], 1); adj[slot] = src[i];     }
            if (d4.y >= lo && d4.y < hi) { int slot = atomicAdd(&write_ptr[d4.y], 1); adj[slot] = src[i + 1]; }
            if (d4.z >= lo && d4.z < hi) { int slot = atomicAdd(&write_ptr[d4.z], 1); adj[slot] = src[i + 2]; }
            if (d4.w >= lo && d4.w < hi) { int slot = atomicAdd(&write_ptr[d4.w], 1); adj[slot] = src[i + 3]; }
        } else {
            for (int k = i; k < e; ++k) {
                int d = dst[k];
                if (d >= lo && d < hi) { int slot = atomicAdd(&write_ptr[d], 1); adj[slot] = src[k]; }
            }
        }
    }
}

// ---------------- xn = x * dis, padded to 20 floats ----------------

__global__ void k_xn(const float* __restrict__ x, const float* __restrict__ dis,
                     float* __restrict__ xn, int n) {
    int gid = blockIdx.x * 256 + threadIdx.x;
    if (gid >= n * 5) return;
    int i = gid / 5, s = gid - (gid / 5) * 5;
    float dn = dis[i];
    const float* xr = x + (size_t)i * IN_DIM;
    float4 v;
    int k = s * 4;
    v.x = (k + 0 < IN_DIM) ? xr[k + 0] * dn : 0.f;
    v.y = (k + 1 < IN_DIM) ? xr[k + 1] * dn : 0.f;
    v.z = (k + 2 < IN_DIM) ? xr[k + 2] * dn : 0.f;
    v.w = (k + 3 < IN_DIM) ? xr[k + 3] * dn : 0.f;
    *(float4*)(xn + (size_t)i * XPAD + k) = v;
}

// ---------------- fused layer 1+2a: gather xn + W1 + relu + W2 --------------
// One wave per node. Gathers 20-float rows (12 edge-groups x 5 lanes, x2
// unroll = 24 in flight), shuffle-tree reduce, LDS broadcast, W1 dot (relu),
// then h row (in lanes via LDS) @ W2 -> hn2 directly. h never hits global.

__global__ void k_agg1f(const float* __restrict__ xn, const int* __restrict__ row_ptr,
                        const int* __restrict__ deg, const int* __restrict__ adj,
                        const float* __restrict__ dis, const float* __restrict__ W1,
                        const float* __restrict__ b1, const float* __restrict__ W2,
                        float* __restrict__ hn2, int n) {
    __shared__ float sw[IN_DIM * HID];
    __shared__ float sw2[HID * EMB];
    __shared__ float sb[HID];
    __shared__ __align__(16) float sagg[4][XPAD];
    __shared__ float sh[4][HID];
    int tid = threadIdx.x;
    for (int t = tid; t < IN_DIM * HID; t += 256) sw[t] = W1[t];
    for (int t = tid; t < HID * EMB; t += 256) sw2[t] = W2[t];
    if (tid < HID) sb[tid] = b1[tid];
    __syncthreads();
    int node = blockIdx.x * 4 + (tid >> 6);
    if (node >= n) return;
    int lane = tid & 63;
    int wv = tid >> 6;
    int eg = lane / 5;               // 0..12 (lanes 60-63 inactive)
    int sl = lane - eg * 5;          // float4 slot 0..4
    bool act = eg < 12;
    int beg = row_ptr[node];
    int cnt = deg[node] - 1;
    const int* a = adj + beg;
    float4 acc = make_float4(0.f, 0.f, 0.f, 0.f);
    int base = 0;
    for (; base + 24 <= cnt; base += 24) {
        if (act) {
            int j0 = a[base + eg];
            int j1 = a[base + 12 + eg];
            float4 v0 = *(const float4*)(xn + (size_t)j0 * XPAD + sl * 4);
            float4 v1 = *(const float4*)(xn + (size_t)j1 * XPAD + sl * 4);
            acc.x += v0.x + v1.x; acc.y += v0.y + v1.y;
            acc.z += v0.z + v1.z; acc.w += v0.w + v1.w;
        }
    }
    if (act && base + eg < cnt) {
        float4 v = *(const float4*)(xn + (size_t)a[base + eg] * XPAD + sl * 4);
        acc.x += v.x; acc.y += v.y; acc.z += v.z; acc.w += v.w;
    }
    if (act && base + 12 + eg < cnt) {
        float4 v = *(const float4*)(xn + (size_t)a[base + 12 + eg] * XPAD + sl * 4);
        acc.x += v.x; acc.y += v.y; acc.z += v.z; acc.w += v.w;
    }
    // reduce 12 groups -> group 0
    float4 t = shfl_f4(acc, lane + 30);
    if (lane < 30) { acc.x += t.x; acc.y += t.y; acc.z += t.z; acc.w += t.w; }
    t = shfl_f4(acc, lane + 15);
    if (lane < 15) { acc.x += t.x; acc.y += t.y; acc.z += t.z; acc.w += t.w; }
    t = shfl_f4(acc, lane + 10);
    if (lane < 5) { acc.x += t.x; acc.y += t.y; acc.z += t.z; acc.w += t.w; }
    t = shfl_f4(acc, lane + 5);
    if (lane < 5) { acc.x += t.x; acc.y += t.y; acc.z += t.z; acc.w += t.w; }
    float dn = dis[node];
    if (lane < 5) {
        float4 s4v = *(const float4*)(xn + (size_t)node * XPAD + lane * 4);
        acc.x += s4v.x; acc.y += s4v.y; acc.z += s4v.z; acc.w += s4v.w;
        *(float4*)&sagg[wv][lane * 4] = acc;   // same-wave LDS
    }
    float s = 0.f;
#pragma unroll
    for (int k = 0; k < IN_DIM; ++k) s += sagg[wv][k] * sw[k * HID + lane];
    float hv = dn * s + sb[lane];
    sh[wv][lane] = hv > 0.f ? hv : 0.f;        // h row stays in LDS
    // fused layer-2 GEMM: hn2[node][g] = dn * sum_k h[k]*W2[k][g]
    int g = lane & 31, half = lane >> 5;
    float s2 = 0.f;
#pragma unroll
    for (int k = 0; k < 32; ++k) s2 += sh[wv][half * 32 + k] * sw2[(half * 32 + k) * EMB + g];
    s2 += __shfl_xor(s2, 32);
    if (half == 0) hn2[(size_t)node * EMB + g] = dn * s2;
}

// ---------------- layer-2 aggregation (float4 per lane, x3 unroll) ----------

__global__ void k_agg2(const float* __restrict__ hn2, const int* __restrict__ row_ptr,
                       const int* __restrict__ deg, const int* __restrict__ adj,
                       const float* __restrict__ dis, const float* __restrict__ b2,
                       float* __restrict__ z, int n) {
    int node = blockIdx.x * 4 + (threadIdx.x >> 6);
    if (node >= n) return;
    int lane = threadIdx.x & 63;
    int eg = lane >> 3;
    int d4 = lane & 7;
    int beg = row_ptr[node];
    int cnt = deg[node] - 1;
    const int* a = adj + beg;
    float4 acc = make_float4(0.f, 0.f, 0.f, 0.f);
    int base = 0;
    for (; base + 24 <= cnt; base += 24) {
        int j0 = a[base + eg];
        int j1 = a[base + 8 + eg];
        int j2 = a[base + 16 + eg];
        float4 v0 = *(const float4*)(hn2 + (size_t)j0 * EMB + d4 * 4);
        float4 v1 = *(const float4*)(hn2 + (size_t)j1 * EMB + d4 * 4);
        float4 v2 = *(const float4*)(hn2 + (size_t)j2 * EMB + d4 * 4);
        acc.x += v0.x + v1.x + v2.x; acc.y += v0.y + v1.y + v2.y;
        acc.z += v0.z + v1.z + v2.z; acc.w += v0.w + v1.w + v2.w;
    }
    int kk = base + eg;
    if (kk < cnt) {
        float4 v = *(const float4*)(hn2 + (size_t)a[kk] * EMB + d4 * 4);
        acc.x += v.x; acc.y += v.y; acc.z += v.z; acc.w += v.w;
    }
    kk += 8;
    if (kk < cnt) {
        float4 v = *(const float4*)(hn2 + (size_t)a[kk] * EMB + d4 * 4);
        acc.x += v.x; acc.y += v.y; acc.z += v.z; acc.w += v.w;
    }
    kk += 8;
    if (kk < cnt) {
        float4 v = *(const float4*)(hn2 + (size_t)a[kk] * EMB + d4 * 4);
        acc.x += v.x; acc.y += v.y; acc.z += v.z; acc.w += v.w;
    }
    float4 t = shfl_xor_f4(acc, 8);
    acc.x += t.x; acc.y += t.y; acc.z += t.z; acc.w += t.w;
    t = shfl_xor_f4(acc, 16);
    acc.x += t.x; acc.y += t.y; acc.z += t.z; acc.w += t.w;
    t = shfl_xor_f4(acc, 32);
    acc.x += t.x; acc.y += t.y; acc.z += t.z; acc.w += t.w;
    if (eg == 0) {
        float4 self = *(const float4*)(hn2 + (size_t)node * EMB + d4 * 4);
        float4 bb = *(const float4*)(b2 + d4 * 4);
        float dn = dis[node];
        float4 o;
        o.x = dn * (acc.x + self.x) + bb.x;
        o.y = dn * (acc.y + self.y) + bb.y;
        o.z = dn * (acc.z + self.z) + bb.z;
        o.w = dn * (acc.w + self.w) + bb.w;
        *(float4*)(z + (size_t)node * EMB + d4 * 4) = o;
    }
}

// ---------------- pair head ----------------

__global__ void k_head(const float* __restrict__ z, const int* __restrict__ tg,
                       const float* __restrict__ Wo, const float* __restrict__ bo,
                       float* __restrict__ out, int btot) {
    int i = blockIdx.x * 256 + threadIdx.x;
    if (i >= btot) return;
    int t0 = tg[i], t1 = tg[btot + i];
    const float* z0 = z + (size_t)t0 * EMB;
    const float* z1 = z + (size_t)t1 * EMB;
    float acc = 0.f;
#pragma unroll
    for (int g = 0; g < EMB; ++g) acc += z0[g] * z1[g] * Wo[g];
    out[i] = acc + bo[0];
}

// ---------------- launch ----------------

extern "C" void kernel_launch(void* const* d_in, const int* in_sizes, int n_in,
                              void* d_out, int out_size, void* d_ws, size_t ws_size,
                              hipStream_t stream) {
    const float* x  = (const float*)d_in[0];
    const int*   ei = (const int*)d_in[1];
    const int*   tg = (const int*)d_in[2];
    const float* W1 = (const float*)d_in[3];
    const float* b1 = (const float*)d_in[4];
    const float* W2 = (const float*)d_in[5];
    const float* b2 = (const float*)d_in[6];
    const float* Wo = (const float*)d_in[7];
    const float* bo = (const float*)d_in[8];
    float* out = (float*)d_out;

    int n = in_sizes[0] / IN_DIM;
    int e = in_sizes[1] / 2;
    int b = in_sizes[2] / 2;
    const int* src = ei;
    const int* dst = ei + e;

    char* ws = (char*)d_ws;
    size_t off = 0;
    auto alloc = [&](size_t bytes) -> char* {
        char* p = ws + off;
        off += (bytes + 255) & ~(size_t)255;
        return p;
    };
    int*   deg       = (int*)alloc((size_t)n * 4);
    int*   row_ptr   = (int*)alloc((size_t)n * 4);
    int*   write_ptr = (int*)alloc((size_t)n * 4);
    int*   blksums   = (int*)alloc(1024 * 4);
    int*   blkoffs   = (int*)alloc(1024 * 4);
    float* dis       = (float*)alloc((size_t)n * 4);
    int*   adj       = (int*)alloc((size_t)e * 4);
    float* xn        = (float*)alloc((size_t)n * XPAD * 4);
    float* bufA      = (float*)alloc((size_t)n * EMB * 4);   // hn2
    float* bufB      = (float*)alloc((size_t)n * EMB * 4);   // z
    int*   gcnt      = (int*)alloc(1024);
    int*   gbase     = (int*)alloc(1024);

    int Pp = (n + 511) >> PSHIFT;
    int meanb = (Pp > 0) ? (e / Pp) : e;
    int cap = meanb + meanb / 16 + 1024;
    size_t bucket_bytes = (size_t)Pp * cap * 8;
    bool use_buckets = (Pp <= PMAX) && ((off + bucket_bytes + 256) <= ws_size);
    u64* gbuf = (u64*)alloc(bucket_bytes);

    int nb1024 = (n + 1023) / 1024;
    int nrange = (n + NGROUP - 1) / NGROUP;

    k_init<<<(n + 255) / 256, 256, 0, stream>>>(deg, gcnt, n);

    if (use_buckets) {
        k_part<<<512, 256, 0, stream>>>(src, dst, gcnt, gbuf, e, Pp, cap);
        k_gscan<<<1, 256, 0, stream>>>(gcnt, gbase, Pp);
        k_build<<<Pp, 512, 0, stream>>>(gbuf, gcnt, gbase, deg, dis, row_ptr, adj, cap, n);
    } else {
        k_count_part<<<2048, 256, 0, stream>>>(dst, deg, e, nrange, n);
        k_dis<<<(n + 255) / 256, 256, 0, stream>>>(deg, dis, n);
        k_scanA<<<nb1024, 1024, 0, stream>>>(deg, row_ptr, blksums, n);
        k_scanB<<<1, 1024, 0, stream>>>(blksums, blkoffs, nb1024);
        k_scanC<<<nb1024, 1024, 0, stream>>>(row_ptr, blkoffs, write_ptr, n);
        k_fill_part<<<2048, 256, 0, stream>>>(src, dst, write_ptr, adj, e, nrange, n);
    }

    k_xn<<<((size_t)n * 5 + 255) / 256, 256, 0, stream>>>(x, dis, xn, n);
    k_agg1f<<<(n + 3) / 4, 256, 0, stream>>>(xn, row_ptr, deg, adj, dis, W1, b1, W2, bufA, n);
    k_agg2<<<(n + 3) / 4, 256, 0, stream>>>(bufA, row_ptr, deg, adj, dis, b2, bufB, n);

    k_head<<<(b + 255) / 256, 256, 0, stream>>>(bufB, tg, Wo, bo, out, b);
}